// Round 1
// baseline (245.922 us; speedup 1.0000x reference)
//
#include <hip/hip_runtime.h>
#include <hip/hip_bf16.h>

// B=2, S=2048, H=16, D=64, D_MODEL=1024, M=B*S=4096
// ws layout (bytes):
//   WT  @ 0MB  : [4][1024][1024] bf16 (w_q^T, w_k^T, w_v^T, w_o^T)  8MB
//   Xb  @ 8MB  : [3][4096][1024] bf16 (q,k,v converted)            24MB
//   Qh  @ 32MB : [32][2048][64]  bf16 (scaled by 0.125*log2e)       8MB
//   Kh  @ 40MB : [32][2048][64]  bf16                               8MB
//   Vt  @ 48MB : [32][64][2048]  bf16 (per-head transposed V)       8MB
//   Ob  @ 56MB : [4096][1024]    bf16 (attention output)            8MB

using bf16x8 = __attribute__((ext_vector_type(8))) short;
using f32x4  = __attribute__((ext_vector_type(4))) float;
typedef unsigned short u16;
using u16x4 = __attribute__((ext_vector_type(4))) u16;
using u16x8 = __attribute__((ext_vector_type(8))) u16;

#define GLDS16(g, l) __builtin_amdgcn_global_load_lds( \
    (const __attribute__((address_space(1))) void*)(g), \
    (__attribute__((address_space(3))) void*)(l), 16, 0, 0)

#if __has_builtin(__builtin_amdgcn_exp2f)
#define EXP2(x) __builtin_amdgcn_exp2f(x)
#else
#define EXP2(x) exp2f(x)
#endif

__device__ __forceinline__ u16 f2bf(float f) {
  unsigned u = __builtin_bit_cast(unsigned, f);
  u += 0x7fffu + ((u >> 16) & 1u);
  return (u16)(u >> 16);
}

// ---------- kernel 1: weight transpose+convert: WT[z][n][k] = bf16(w_z[k][n]) ----------
__global__ __launch_bounds__(256) void wtrans_kernel(
    const float* __restrict__ wq, const float* __restrict__ wk,
    const float* __restrict__ wv, const float* __restrict__ wo,
    u16* __restrict__ dst) {
  __shared__ float t[32][33];
  const int z = blockIdx.z;
  const float* src = (z == 0) ? wq : (z == 1) ? wk : (z == 2) ? wv : wo;
  u16* d = dst + (size_t)z * 1024 * 1024;
  const int tx = threadIdx.x & 31, ty = threadIdx.x >> 5;
  const int bx = blockIdx.x * 32, by = blockIdx.y * 32;
#pragma unroll
  for (int j = 0; j < 4; j++)
    t[ty + j * 8][tx] = src[(size_t)(by + ty + j * 8) * 1024 + bx + tx];
  __syncthreads();
#pragma unroll
  for (int j = 0; j < 4; j++)
    d[(size_t)(bx + ty + j * 8) * 1024 + by + tx] = f2bf(t[tx][ty + j * 8]);
}

// ---------- kernel 2: convert q,k,v fp32 -> bf16 ----------
__global__ __launch_bounds__(256) void cvt_in_kernel(
    const float* __restrict__ q, const float* __restrict__ k,
    const float* __restrict__ v, u16* __restrict__ dst) {
  const int z = blockIdx.y;
  const float* src = (z == 0) ? q : (z == 1) ? k : v;
  u16* d = dst + (size_t)z * 4096 * 1024;
  size_t i = ((size_t)blockIdx.x * 256 + threadIdx.x) * 4;
  float4 f = *(const float4*)(src + i);
  u16x4 o;
  o.x = f2bf(f.x); o.y = f2bf(f.y); o.z = f2bf(f.z); o.w = f2bf(f.w);
  *(u16x4*)(d + i) = o;
}

// ---------- shared GEMM core: 128x128 tile, BK=64, swizzled LDS, global_load_lds ----------
// A row-major [*,1024], B row-major [N][K]=[*,1024] (pre-transposed weights).
__device__ __forceinline__ void gemm128(const u16* __restrict__ A,
                                        const u16* __restrict__ B,
                                        int arow0, int bcol0,
                                        u16* ldsA, u16* ldsB,
                                        f32x4 acc[4][4]) {
  const int tid = threadIdx.x;
  const int lane = tid & 63, wave = tid >> 6;
  const int lr = lane & 15, lg = lane >> 4;
  const int wr = (wave >> 1) * 64, wc = (wave & 1) * 64;
  for (int kt = 0; kt < 1024; kt += 64) {
#pragma unroll
    for (int i = 0; i < 4; i++) {
      int o = (i * 256 + tid) * 8;
      int row = o >> 6, ch = (o >> 3) & 7;
      int sc = (ch ^ (row & 7)) << 3;  // inverse-swizzled source chunk
      GLDS16(A + (size_t)(arow0 + row) * 1024 + kt + sc, &ldsA[o]);
      GLDS16(B + (size_t)(bcol0 + row) * 1024 + kt + sc, &ldsB[o]);
    }
    __syncthreads();
#pragma unroll
    for (int kk = 0; kk < 2; kk++) {
      bf16x8 af[4], bfr[4];
      const int ke = kk * 32 + lg * 8;
#pragma unroll
      for (int m = 0; m < 4; m++) {
        int row = wr + m * 16 + lr;
        af[m] = *(const bf16x8*)&ldsA[row * 64 + (ke ^ ((row & 7) << 3))];
      }
#pragma unroll
      for (int n = 0; n < 4; n++) {
        int row = wc + n * 16 + lr;
        bfr[n] = *(const bf16x8*)&ldsB[row * 64 + (ke ^ ((row & 7) << 3))];
      }
#pragma unroll
      for (int m = 0; m < 4; m++)
#pragma unroll
        for (int n = 0; n < 4; n++)
          acc[m][n] = __builtin_amdgcn_mfma_f32_16x16x32_bf16(af[m], bfr[n],
                                                              acc[m][n], 0, 0, 0);
    }
    __syncthreads();
  }
}

// ---------- kernel 3: QKV projections ----------
__global__ __launch_bounds__(256) void proj_kernel(
    const u16* __restrict__ Xb, const u16* __restrict__ WT,
    u16* __restrict__ Qh, u16* __restrict__ Kh, u16* __restrict__ Vt) {
  __shared__ u16 lds[16384];
  const int z = blockIdx.z;
  const u16* A = Xb + (size_t)z * 4096 * 1024;
  const u16* B = WT + (size_t)z * 1024 * 1024;
  const int arow0 = blockIdx.y * 128, bcol0 = blockIdx.x * 128;
  f32x4 acc[4][4] = {};
  gemm128(A, B, arow0, bcol0, lds, lds + 8192, acc);

  const int lane = threadIdx.x & 63, wave = threadIdx.x >> 6;
  const int lr = lane & 15, lg = lane >> 4;
  const int wr = (wave >> 1) * 64, wc = (wave & 1) * 64;

  if (z == 2) {
    // V: transpose through LDS -> Vt[(b*16+h)*64+d][s]
    u16* T = lds;  // [128 c][128 s], swizzled rows
#pragma unroll
    for (int m = 0; m < 4; m++)
#pragma unroll
      for (int n = 0; n < 4; n++)
#pragma unroll
        for (int r = 0; r < 4; r++) {
          int sl = wr + m * 16 + lg * 4 + r;
          int cl = wc + n * 16 + lr;
          T[cl * 128 + (sl ^ ((cl & 7) << 3))] = f2bf(acc[m][n][r]);
        }
    __syncthreads();
    const int t = threadIdx.x;
    const int cl = t >> 1, s0 = (t & 1) * 64;
    const int gc = bcol0 + cl;
    const size_t vrow = ((size_t)(arow0 >> 11) * 16 + (gc >> 6)) * 64 + (gc & 63);
#pragma unroll
    for (int j = 0; j < 8; j++) {
      int sl = s0 + j * 8;
      u16x8 vv = *(const u16x8*)&T[cl * 128 + (sl ^ ((cl & 7) << 3))];
      *(u16x8*)&Vt[vrow * 2048 + (size_t)((arow0 & 2047) + sl)] = vv;
    }
  } else {
    const float scale = (z == 0) ? 0.18033688f : 1.0f;  // 0.125 * log2(e)
    u16* dst = (z == 0) ? Qh : Kh;
#pragma unroll
    for (int m = 0; m < 4; m++)
#pragma unroll
      for (int n = 0; n < 4; n++)
#pragma unroll
        for (int r = 0; r < 4; r++) {
          int gr = arow0 + wr + m * 16 + lg * 4 + r;
          int gc = bcol0 + wc + n * 16 + lr;
          size_t idx = (((size_t)(gr >> 11) * 16 + (gc >> 6)) * 2048 +
                        (gr & 2047)) * 64 + (gc & 63);
          dst[idx] = f2bf(acc[m][n][r] * scale);
        }
  }
}

// ---------- kernel 4: flash attention ----------
__global__ __launch_bounds__(256) void attn_kernel(
    const u16* __restrict__ Qh, const u16* __restrict__ Kh,
    const u16* __restrict__ Vt, u16* __restrict__ Ob) {
  __shared__ u16 kt[128 * 64];   // K tile [key][d], swizzled rows of 64
  __shared__ u16 vt[64 * 128];   // V^T tile [d][s], swizzled rows of 128
  __shared__ u16 pt[4 * 32 * 128];  // per-wave P [32 q][128 k], swizzled
  const int tid = threadIdx.x;
  const int lane = tid & 63, wave = tid >> 6;
  const int lr = lane & 15, lg = lane >> 4;
  const int bh = blockIdx.y;
  const int q0 = blockIdx.x * 128;
  const u16* Qb = Qh + ((size_t)bh * 2048 + q0) * 64;
  const u16* Kb = Kh + (size_t)bh * 2048 * 64;
  const u16* Vb = Vt + (size_t)bh * 64 * 2048;
  u16* ptw = pt + wave * 4096;

  bf16x8 aq[2][2];
#pragma unroll
  for (int m = 0; m < 2; m++)
#pragma unroll
    for (int kk = 0; kk < 2; kk++)
      aq[m][kk] = *(const bf16x8*)(Qb + (wave * 32 + m * 16 + lr) * 64 +
                                   kk * 32 + lg * 8);

  f32x4 oacc[2][4] = {};
  float mrun[2][4], lrun[2][4];
#pragma unroll
  for (int m = 0; m < 2; m++)
#pragma unroll
    for (int r = 0; r < 4; r++) { mrun[m][r] = -1e30f; lrun[m][r] = 0.f; }

  for (int ktile = 0; ktile < 16; ++ktile) {
#pragma unroll
    for (int i = 0; i < 4; i++) {
      int o = (i * 256 + tid) * 8;
      {
        int row = o >> 6, ch = (o >> 3) & 7;
        GLDS16(Kb + (size_t)(ktile * 128 + row) * 64 + ((ch ^ (row & 7)) << 3),
               &kt[o]);
      }
      {
        int d = o >> 7, ch = (o >> 3) & 15;
        GLDS16(Vb + (size_t)d * 2048 + ktile * 128 + ((ch ^ (d & 7)) << 3),
               &vt[o]);
      }
    }
    __syncthreads();

    // S = Q' K^T (log2 domain: Q prescaled by 0.125*log2e)
    f32x4 sacc[2][8] = {};
#pragma unroll
    for (int kk = 0; kk < 2; kk++) {
      const int ke = kk * 32 + lg * 8;
#pragma unroll
      for (int n = 0; n < 8; n++) {
        int row = n * 16 + lr;
        bf16x8 bk = *(const bf16x8*)&kt[row * 64 + (ke ^ ((row & 7) << 3))];
        sacc[0][n] = __builtin_amdgcn_mfma_f32_16x16x32_bf16(aq[0][kk], bk,
                                                             sacc[0][n], 0, 0, 0);
        sacc[1][n] = __builtin_amdgcn_mfma_f32_16x16x32_bf16(aq[1][kk], bk,
                                                             sacc[1][n], 0, 0, 0);
      }
    }

    // online softmax (exp2 domain); write P to per-wave LDS
#pragma unroll
    for (int m = 0; m < 2; m++) {
#pragma unroll
      for (int r = 0; r < 4; r++) {
        float smax = sacc[m][0][r];
#pragma unroll
        for (int n = 1; n < 8; n++) smax = fmaxf(smax, sacc[m][n][r]);
        smax = fmaxf(smax, __shfl_xor(smax, 1));
        smax = fmaxf(smax, __shfl_xor(smax, 2));
        smax = fmaxf(smax, __shfl_xor(smax, 4));
        smax = fmaxf(smax, __shfl_xor(smax, 8));
        float mnew = fmaxf(mrun[m][r], smax);
        float corr = EXP2(mrun[m][r] - mnew);
        mrun[m][r] = mnew;
        const int row = m * 16 + lg * 4 + r;
        float psum = 0.f;
#pragma unroll
        for (int n = 0; n < 8; n++) {
          float p = EXP2(sacc[m][n][r] - mnew);
          psum += p;
          ptw[row * 128 + ((n * 16 + lr) ^ ((row & 7) << 3))] = f2bf(p);
        }
        psum += __shfl_xor(psum, 1);
        psum += __shfl_xor(psum, 2);
        psum += __shfl_xor(psum, 4);
        psum += __shfl_xor(psum, 8);
        lrun[m][r] = lrun[m][r] * corr + psum;
#pragma unroll
        for (int n = 0; n < 4; n++) oacc[m][n][r] *= corr;
      }
    }
    __syncthreads();  // order P writes before P reads (and keep waves together)

    // O += P V
#pragma unroll
    for (int ks = 0; ks < 4; ks++) {
      const int ke = ks * 32 + lg * 8;
      bf16x8 ap[2], bv[4];
#pragma unroll
      for (int m = 0; m < 2; m++) {
        int row = m * 16 + lr;
        ap[m] = *(const bf16x8*)&ptw[row * 128 + (ke ^ ((row & 7) << 3))];
      }
#pragma unroll
      for (int n = 0; n < 4; n++) {
        int d = n * 16 + lr;
        bv[n] = *(const bf16x8*)&vt[d * 128 + (ke ^ ((d & 7) << 3))];
      }
#pragma unroll
      for (int m = 0; m < 2; m++)
#pragma unroll
        for (int n = 0; n < 4; n++)
          oacc[m][n] = __builtin_amdgcn_mfma_f32_16x16x32_bf16(ap[m], bv[n],
                                                               oacc[m][n], 0, 0, 0);
    }
    __syncthreads();  // before restaging kt/vt
  }

  // epilogue: normalize, store O as [B,S,H*D] bf16
  const int b = bh >> 4, h = bh & 15;
#pragma unroll
  for (int m = 0; m < 2; m++)
#pragma unroll
    for (int r = 0; r < 4; r++) {
      float inv = 1.0f / lrun[m][r];
      int qrow = q0 + wave * 32 + m * 16 + lg * 4 + r;
#pragma unroll
      for (int n = 0; n < 4; n++) {
        int d = n * 16 + lr;
        Ob[((size_t)b * 2048 + qrow) * 1024 + h * 64 + d] =
            f2bf(oacc[m][n][r] * inv);
      }
    }
}

// ---------- kernel 5: output projection -> fp32 d_out ----------
__global__ __launch_bounds__(256) void outproj_kernel(
    const u16* __restrict__ Ob, const u16* __restrict__ WoT,
    float* __restrict__ out) {
  __shared__ u16 lds[16384];
  const int arow0 = blockIdx.y * 128, bcol0 = blockIdx.x * 128;
  f32x4 acc[4][4] = {};
  gemm128(Ob, WoT, arow0, bcol0, lds, lds + 8192, acc);
  const int lane = threadIdx.x & 63, wave = threadIdx.x >> 6;
  const int lr = lane & 15, lg = lane >> 4;
  const int wr = (wave >> 1) * 64, wc = (wave & 1) * 64;
#pragma unroll
  for (int m = 0; m < 4; m++)
#pragma unroll
    for (int n = 0; n < 4; n++)
#pragma unroll
      for (int r = 0; r < 4; r++) {
        int gr = arow0 + wr + m * 16 + lg * 4 + r;
        int gc = bcol0 + wc + n * 16 + lr;
        out[(size_t)gr * 1024 + gc] = acc[m][n][r];
      }
}

extern "C" void kernel_launch(void* const* d_in, const int* in_sizes, int n_in,
                              void* d_out, int out_size, void* d_ws, size_t ws_size,
                              hipStream_t stream) {
  const float* q  = (const float*)d_in[0];
  const float* k  = (const float*)d_in[1];
  const float* v  = (const float*)d_in[2];
  const float* wq = (const float*)d_in[3];
  const float* wk = (const float*)d_in[4];
  const float* wv = (const float*)d_in[5];
  const float* wo = (const float*)d_in[6];
  float* out = (float*)d_out;
  char* ws = (char*)d_ws;

  u16* WT = (u16*)ws;                                    // [4][1024][1024]
  u16* Xb = (u16*)(ws + (size_t)8  * 1024 * 1024);       // [3][4096][1024]
  u16* Qh = (u16*)(ws + (size_t)32 * 1024 * 1024);       // [32][2048][64]
  u16* Kh = (u16*)(ws + (size_t)40 * 1024 * 1024);       // [32][2048][64]
  u16* Vt = (u16*)(ws + (size_t)48 * 1024 * 1024);       // [32][64][2048]
  u16* Ob = (u16*)(ws + (size_t)56 * 1024 * 1024);       // [4096][1024]

  wtrans_kernel<<<dim3(32, 32, 4), 256, 0, stream>>>(wq, wk, wv, wo, WT);
  cvt_in_kernel<<<dim3(4096, 3), 256, 0, stream>>>(q, k, v, Xb);
  proj_kernel<<<dim3(8, 32, 3), 256, 0, stream>>>(Xb, WT, Qh, Kh, Vt);
  attn_kernel<<<dim3(16, 32), 256, 0, stream>>>(Qh, Kh, Vt, Ob);
  outproj_kernel<<<dim3(8, 32), 256, 0, stream>>>(Ob, WT + (size_t)3 * 1024 * 1024, out);
}

// Round 3
// 194.273 us; speedup vs baseline: 1.2659x; 1.2659x over previous
//
#include <hip/hip_runtime.h>
#include <hip/hip_bf16.h>

// B=2, S=2048, H=16, D=64, D_MODEL=1024, M=B*S=4096
// ws layout (bytes):
//   WT  @ 0MB  : [4][1024][1024] bf16 (w_q^T, w_k^T, w_v^T, w_o^T)  8MB
//   Xb  @ 8MB  : [3][4096][1024] bf16 (q,k,v converted)            24MB
//   Qh  @ 32MB : [32][2048][64]  bf16 (scaled by 0.125*log2e)       8MB
//   Kh  @ 40MB : [32][2048][64]  bf16                               8MB
//   Vt  @ 48MB : [32][64][2048]  bf16 (per-head transposed V)       8MB
//   Ob  @ 56MB : [4096][1024]    bf16 (attention output)            8MB

using bf16x8 = __attribute__((ext_vector_type(8))) short;
using f32x4  = __attribute__((ext_vector_type(4))) float;
typedef unsigned short u16;
using u16x4 = __attribute__((ext_vector_type(4))) u16;
using u16x8 = __attribute__((ext_vector_type(8))) u16;

#define GLDS16(g, l) __builtin_amdgcn_global_load_lds( \
    (const __attribute__((address_space(1))) void*)(g), \
    (__attribute__((address_space(3))) void*)(l), 16, 0, 0)

#if __has_builtin(__builtin_amdgcn_exp2f)
#define EXP2(x) __builtin_amdgcn_exp2f(x)
#else
#define EXP2(x) exp2f(x)
#endif

// Raw s_barrier is IntrNoMem: pair it with compiler memory fences so LDS
// reads/writes cannot be moved across it at compile time (the HW latency
// margin makes this race rare -> small absmax corruption, seen in R2).
__device__ __forceinline__ void block_sync() {
  __builtin_amdgcn_sched_barrier(0);
  asm volatile("" ::: "memory");
  __builtin_amdgcn_s_barrier();
  asm volatile("" ::: "memory");
  __builtin_amdgcn_sched_barrier(0);
}

__device__ __forceinline__ u16 f2bf(float f) {
  unsigned u = __builtin_bit_cast(unsigned, f);
  u += 0x7fffu + ((u >> 16) & 1u);
  return (u16)(u >> 16);
}

// ---------- kernel 1: weight transpose+convert: WT[z][n][k] = bf16(w_z[k][n]) ----------
__global__ __launch_bounds__(256) void wtrans_kernel(
    const float* __restrict__ wq, const float* __restrict__ wk,
    const float* __restrict__ wv, const float* __restrict__ wo,
    u16* __restrict__ dst) {
  __shared__ float t[32][33];
  const int z = blockIdx.z;
  const float* src = (z == 0) ? wq : (z == 1) ? wk : (z == 2) ? wv : wo;
  u16* d = dst + (size_t)z * 1024 * 1024;
  const int tx = threadIdx.x & 31, ty = threadIdx.x >> 5;
  const int bx = blockIdx.x * 32, by = blockIdx.y * 32;
#pragma unroll
  for (int j = 0; j < 4; j++)
    t[ty + j * 8][tx] = src[(size_t)(by + ty + j * 8) * 1024 + bx + tx];
  __syncthreads();
#pragma unroll
  for (int j = 0; j < 4; j++)
    d[(size_t)(bx + ty + j * 8) * 1024 + by + tx] = f2bf(t[tx][ty + j * 8]);
}

// ---------- kernel 2: convert q,k,v fp32 -> bf16 ----------
__global__ __launch_bounds__(256) void cvt_in_kernel(
    const float* __restrict__ q, const float* __restrict__ k,
    const float* __restrict__ v, u16* __restrict__ dst) {
  const int z = blockIdx.y;
  const float* src = (z == 0) ? q : (z == 1) ? k : v;
  u16* d = dst + (size_t)z * 4096 * 1024;
  size_t i = ((size_t)blockIdx.x * 256 + threadIdx.x) * 4;
  float4 f = *(const float4*)(src + i);
  u16x4 o;
  o.x = f2bf(f.x); o.y = f2bf(f.y); o.z = f2bf(f.z); o.w = f2bf(f.w);
  *(u16x4*)(d + i) = o;
}

// ---------- shared GEMM core: 128x128 tile, BK=64, swizzled LDS, global_load_lds ----------
// A row-major [*,1024], B row-major [N][K]=[*,1024] (pre-transposed weights).
__device__ __forceinline__ void gemm128(const u16* __restrict__ A,
                                        const u16* __restrict__ B,
                                        int arow0, int bcol0,
                                        u16* ldsA, u16* ldsB,
                                        f32x4 acc[4][4]) {
  const int tid = threadIdx.x;
  const int lane = tid & 63, wave = tid >> 6;
  const int lr = lane & 15, lg = lane >> 4;
  const int wr = (wave >> 1) * 64, wc = (wave & 1) * 64;
  for (int kt = 0; kt < 1024; kt += 64) {
#pragma unroll
    for (int i = 0; i < 4; i++) {
      int o = (i * 256 + tid) * 8;
      int row = o >> 6, ch = (o >> 3) & 7;
      int sc = (ch ^ (row & 7)) << 3;  // inverse-swizzled source chunk
      GLDS16(A + (size_t)(arow0 + row) * 1024 + kt + sc, &ldsA[o]);
      GLDS16(B + (size_t)(bcol0 + row) * 1024 + kt + sc, &ldsB[o]);
    }
    __syncthreads();
#pragma unroll
    for (int kk = 0; kk < 2; kk++) {
      bf16x8 af[4], bfr[4];
      const int ke = kk * 32 + lg * 8;
#pragma unroll
      for (int m = 0; m < 4; m++) {
        int row = wr + m * 16 + lr;
        af[m] = *(const bf16x8*)&ldsA[row * 64 + (ke ^ ((row & 7) << 3))];
      }
#pragma unroll
      for (int n = 0; n < 4; n++) {
        int row = wc + n * 16 + lr;
        bfr[n] = *(const bf16x8*)&ldsB[row * 64 + (ke ^ ((row & 7) << 3))];
      }
#pragma unroll
      for (int m = 0; m < 4; m++)
#pragma unroll
        for (int n = 0; n < 4; n++)
          acc[m][n] = __builtin_amdgcn_mfma_f32_16x16x32_bf16(af[m], bfr[n],
                                                              acc[m][n], 0, 0, 0);
    }
    __syncthreads();
  }
}

// ---------- kernel 3: QKV projections ----------
__global__ __launch_bounds__(256) void proj_kernel(
    const u16* __restrict__ Xb, const u16* __restrict__ WT,
    u16* __restrict__ Qh, u16* __restrict__ Kh, u16* __restrict__ Vt) {
  __shared__ u16 lds[16384];
  const int z = blockIdx.z;
  const u16* A = Xb + (size_t)z * 4096 * 1024;
  const u16* B = WT + (size_t)z * 1024 * 1024;
  const int arow0 = blockIdx.y * 128, bcol0 = blockIdx.x * 128;
  f32x4 acc[4][4] = {};
  gemm128(A, B, arow0, bcol0, lds, lds + 8192, acc);

  const int lane = threadIdx.x & 63, wave = threadIdx.x >> 6;
  const int lr = lane & 15, lg = lane >> 4;
  const int wr = (wave >> 1) * 64, wc = (wave & 1) * 64;

  if (z == 2) {
    // V: transpose through LDS -> Vt[(b*16+h)*64+d][s]
    u16* T = lds;  // [128 c][128 s], swizzled rows
#pragma unroll
    for (int m = 0; m < 4; m++)
#pragma unroll
      for (int n = 0; n < 4; n++)
#pragma unroll
        for (int r = 0; r < 4; r++) {
          int sl = wr + m * 16 + lg * 4 + r;
          int cl = wc + n * 16 + lr;
          T[cl * 128 + (sl ^ ((cl & 7) << 3))] = f2bf(acc[m][n][r]);
        }
    __syncthreads();
    const int t = threadIdx.x;
    const int cl = t >> 1, s0 = (t & 1) * 64;
    const int gc = bcol0 + cl;
    const size_t vrow = ((size_t)(arow0 >> 11) * 16 + (gc >> 6)) * 64 + (gc & 63);
#pragma unroll
    for (int j = 0; j < 8; j++) {
      int sl = s0 + j * 8;
      u16x8 vv = *(const u16x8*)&T[cl * 128 + (sl ^ ((cl & 7) << 3))];
      *(u16x8*)&Vt[vrow * 2048 + (size_t)((arow0 & 2047) + sl)] = vv;
    }
  } else {
    const float scale = (z == 0) ? 0.18033688f : 1.0f;  // 0.125 * log2(e)
    u16* dst = (z == 0) ? Qh : Kh;
#pragma unroll
    for (int m = 0; m < 4; m++)
#pragma unroll
      for (int n = 0; n < 4; n++)
#pragma unroll
        for (int r = 0; r < 4; r++) {
          int gr = arow0 + wr + m * 16 + lg * 4 + r;
          int gc = bcol0 + wc + n * 16 + lr;
          size_t idx = (((size_t)(gr >> 11) * 16 + (gc >> 6)) * 2048 +
                        (gr & 2047)) * 64 + (gc & 63);
          dst[idx] = f2bf(acc[m][n][r] * scale);
        }
  }
}

// ---------- kernel 4: flash attention (KVBLK=64, dbuf staging, counted vmcnt) ----------
// grid (32 qblocks, 32 bh), 4 waves/block, 16 q-rows per wave. LDS = 40KB -> 4 blocks/CU.
__global__ __launch_bounds__(256, 4) void attn_kernel(
    const u16* __restrict__ Qh, const u16* __restrict__ Kh,
    const u16* __restrict__ Vt, u16* __restrict__ Ob) {
  __shared__ u16 kt[2][64 * 64];  // K tile [key][d], swizzled rows of 64
  __shared__ u16 vt[2][64 * 64];  // V^T tile [d][s], swizzled rows of 64
  __shared__ u16 pt[4][16 * 64];  // per-wave P [16 q][64 k], swizzled
  const int tid = threadIdx.x;
  const int lane = tid & 63, wave = tid >> 6;
  const int lr = lane & 15, lg = lane >> 4;
  const int bh = blockIdx.y;
  const int q0 = blockIdx.x * 64;
  const u16* Qb = Qh + ((size_t)bh * 2048 + q0) * 64;
  const u16* Kb = Kh + (size_t)bh * 2048 * 64;
  const u16* Vb = Vt + (size_t)bh * 64 * 2048;
  u16* ptw = pt[wave];

  bf16x8 aq[2];
#pragma unroll
  for (int kk = 0; kk < 2; kk++)
    aq[kk] = *(const bf16x8*)(Qb + (wave * 16 + lr) * 64 + kk * 32 + lg * 8);

  f32x4 oacc[4] = {};
  float mrun[4], lrun[4];
#pragma unroll
  for (int r = 0; r < 4; r++) { mrun[r] = -1e30f; lrun[r] = 0.f; }

  // stage tile t into buffer b: 4 global_load_lds per thread (2 K + 2 V)
  auto STAGE = [&](int t, int b) {
#pragma unroll
    for (int i = 0; i < 2; i++) {
      int o = (i * 256 + tid) * 8;
      int row = o >> 6, ch = (o >> 3) & 7;
      int sw = (ch ^ (row & 7)) << 3;
      GLDS16(Kb + (size_t)(t * 64 + row) * 64 + sw, &kt[b][o]);
      GLDS16(Vb + (size_t)row * 2048 + t * 64 + sw, &vt[b][o]);
    }
  };

  auto COMPUTE = [&](int cur) {
    // S = Q' K^T (log2 domain: Q prescaled by 0.125*log2e)
    f32x4 sacc[4] = {};
#pragma unroll
    for (int kk = 0; kk < 2; kk++) {
      const int ke = kk * 32 + lg * 8;
#pragma unroll
      for (int n = 0; n < 4; n++) {
        int row = n * 16 + lr;
        bf16x8 bk = *(const bf16x8*)&kt[cur][row * 64 + (ke ^ ((row & 7) << 3))];
        sacc[n] = __builtin_amdgcn_mfma_f32_16x16x32_bf16(aq[kk], bk,
                                                          sacc[n], 0, 0, 0);
      }
    }
    // online softmax (exp2 domain); P to per-wave LDS
#pragma unroll
    for (int r = 0; r < 4; r++) {
      float smax = fmaxf(fmaxf(sacc[0][r], sacc[1][r]),
                         fmaxf(sacc[2][r], sacc[3][r]));
      smax = fmaxf(smax, __shfl_xor(smax, 1));
      smax = fmaxf(smax, __shfl_xor(smax, 2));
      smax = fmaxf(smax, __shfl_xor(smax, 4));
      smax = fmaxf(smax, __shfl_xor(smax, 8));
      float mnew = fmaxf(mrun[r], smax);
      float corr = EXP2(mrun[r] - mnew);
      mrun[r] = mnew;
      const int row = lg * 4 + r;
      float psum = 0.f;
#pragma unroll
      for (int n = 0; n < 4; n++) {
        float p = EXP2(sacc[n][r] - mnew);
        psum += p;
        ptw[row * 64 + ((n * 16 + lr) ^ ((row & 7) << 3))] = f2bf(p);
      }
      psum += __shfl_xor(psum, 1);
      psum += __shfl_xor(psum, 2);
      psum += __shfl_xor(psum, 4);
      psum += __shfl_xor(psum, 8);
      lrun[r] = lrun[r] * corr + psum;
#pragma unroll
      for (int n = 0; n < 4; n++) oacc[n][r] *= corr;
    }
    // drain P ds_writes before cross-lane P ds_reads (belt + suspenders;
    // same-wave DS is documented in-order, but fence it explicitly)
    __builtin_amdgcn_sched_barrier(0);
    asm volatile("s_waitcnt lgkmcnt(0)" ::: "memory");
    __builtin_amdgcn_sched_barrier(0);
    // O += P V
#pragma unroll
    for (int ks = 0; ks < 2; ks++) {
      const int ke = ks * 32 + lg * 8;
      bf16x8 ap = *(const bf16x8*)&ptw[lr * 64 + (ke ^ ((lr & 7) << 3))];
      bf16x8 bv[4];
#pragma unroll
      for (int n = 0; n < 4; n++) {
        int d = n * 16 + lr;
        bv[n] = *(const bf16x8*)&vt[cur][d * 64 + (ke ^ ((d & 7) << 3))];
      }
#pragma unroll
      for (int n = 0; n < 4; n++)
        oacc[n] = __builtin_amdgcn_mfma_f32_16x16x32_bf16(ap, bv[n],
                                                          oacc[n], 0, 0, 0);
    }
  };

  STAGE(0, 0);
  for (int t = 0; t < 31; ++t) {
    STAGE(t + 1, (t + 1) & 1);  // prefetch next tile into other buffer
    asm volatile("s_waitcnt vmcnt(4)" ::: "memory");  // tile t landed; t+1 in flight
    block_sync();               // all waves: tile t fully in LDS
    COMPUTE(t & 1);
    block_sync();               // all waves done reading buf before overwrite
  }
  asm volatile("s_waitcnt vmcnt(0)" ::: "memory");
  block_sync();
  COMPUTE(1);  // tile 31 is in buffer 1

  // epilogue: normalize, store O as [B,S,H*D] bf16
  const int b = bh >> 4, h = bh & 15;
#pragma unroll
  for (int r = 0; r < 4; r++) {
    float inv = 1.0f / lrun[r];
    int qrow = q0 + wave * 16 + lg * 4 + r;
#pragma unroll
    for (int n = 0; n < 4; n++) {
      int d = n * 16 + lr;
      Ob[((size_t)b * 2048 + qrow) * 1024 + h * 64 + d] = f2bf(oacc[n][r] * inv);
    }
  }
}

// ---------- kernel 5: output projection -> fp32 d_out ----------
__global__ __launch_bounds__(256) void outproj_kernel(
    const u16* __restrict__ Ob, const u16* __restrict__ WoT,
    float* __restrict__ out) {
  __shared__ u16 lds[16384];
  const int arow0 = blockIdx.y * 128, bcol0 = blockIdx.x * 128;
  f32x4 acc[4][4] = {};
  gemm128(Ob, WoT, arow0, bcol0, lds, lds + 8192, acc);
  const int lane = threadIdx.x & 63, wave = threadIdx.x >> 6;
  const int lr = lane & 15, lg = lane >> 4;
  const int wr = (wave >> 1) * 64, wc = (wave & 1) * 64;
#pragma unroll
  for (int m = 0; m < 4; m++)
#pragma unroll
    for (int n = 0; n < 4; n++)
#pragma unroll
      for (int r = 0; r < 4; r++) {
        int gr = arow0 + wr + m * 16 + lg * 4 + r;
        int gc = bcol0 + wc + n * 16 + lr;
        out[(size_t)gr * 1024 + gc] = acc[m][n][r];
      }
}

extern "C" void kernel_launch(void* const* d_in, const int* in_sizes, int n_in,
                              void* d_out, int out_size, void* d_ws, size_t ws_size,
                              hipStream_t stream) {
  const float* q  = (const float*)d_in[0];
  const float* k  = (const float*)d_in[1];
  const float* v  = (const float*)d_in[2];
  const float* wq = (const float*)d_in[3];
  const float* wk = (const float*)d_in[4];
  const float* wv = (const float*)d_in[5];
  const float* wo = (const float*)d_in[6];
  float* out = (float*)d_out;
  char* ws = (char*)d_ws;

  u16* WT = (u16*)ws;                                    // [4][1024][1024]
  u16* Xb = (u16*)(ws + (size_t)8  * 1024 * 1024);       // [3][4096][1024]
  u16* Qh = (u16*)(ws + (size_t)32 * 1024 * 1024);       // [32][2048][64]
  u16* Kh = (u16*)(ws + (size_t)40 * 1024 * 1024);       // [32][2048][64]
  u16* Vt = (u16*)(ws + (size_t)48 * 1024 * 1024);       // [32][64][2048]
  u16* Ob = (u16*)(ws + (size_t)56 * 1024 * 1024);       // [4096][1024]

  wtrans_kernel<<<dim3(32, 32, 4), 256, 0, stream>>>(wq, wk, wv, wo, WT);
  cvt_in_kernel<<<dim3(4096, 3), 256, 0, stream>>>(q, k, v, Xb);
  proj_kernel<<<dim3(8, 32, 3), 256, 0, stream>>>(Xb, WT, Qh, Kh, Vt);
  attn_kernel<<<dim3(32, 32), 256, 0, stream>>>(Qh, Kh, Vt, Ob);
  outproj_kernel<<<dim3(8, 32), 256, 0, stream>>>(Ob, WT + (size_t)3 * 1024 * 1024, out);
}

// Round 5
// 155.274 us; speedup vs baseline: 1.5838x; 1.2512x over previous
//
#include <hip/hip_runtime.h>
#include <hip/hip_bf16.h>

// B=2, S=2048, H=16, D=64, D_MODEL=1024, M=B*S=4096
// ws layout (bytes):
//   WT  @ 0MB  : [4][1024][1024] bf16 (w_q^T, w_k^T, w_v^T, w_o^T)  8MB
//   Xb  @ 8MB  : [3][4096][1024] bf16 (q,k,v converted)            24MB
//   Qh  @ 32MB : [32][2048][64]  bf16 (scaled by 0.125*log2e)       8MB
//   Kh  @ 40MB : [32][2048][64]  bf16                               8MB
//   Vt  @ 48MB : [32][64][2048]  bf16 (per-head transposed V)       8MB
//   Ob  @ 56MB : [4096][1024]    bf16 (attention output)            8MB

using bf16x8 = __attribute__((ext_vector_type(8))) short;
using f32x4  = __attribute__((ext_vector_type(4))) float;
using u32x4  = __attribute__((ext_vector_type(4))) unsigned;
typedef unsigned short u16;
using u16x4 = __attribute__((ext_vector_type(4))) u16;
using u16x8 = __attribute__((ext_vector_type(8))) u16;

#define GLDS16(g, l) __builtin_amdgcn_global_load_lds( \
    (const __attribute__((address_space(1))) void*)(g), \
    (__attribute__((address_space(3))) void*)(l), 16, 0, 0)

#if __has_builtin(__builtin_amdgcn_exp2f)
#define EXP2(x) __builtin_amdgcn_exp2f(x)
#else
#define EXP2(x) exp2f(x)
#endif

// Raw s_barrier is IntrNoMem: pair it with compiler memory fences so LDS
// reads/writes cannot be moved across it at compile time.
__device__ __forceinline__ void block_sync() {
  __builtin_amdgcn_sched_barrier(0);
  asm volatile("" ::: "memory");
  __builtin_amdgcn_s_barrier();
  asm volatile("" ::: "memory");
  __builtin_amdgcn_sched_barrier(0);
}

__device__ __forceinline__ u16 f2bf(float f) {
  unsigned u = __builtin_bit_cast(unsigned, f);
  u += 0x7fffu + ((u >> 16) & 1u);
  return (u16)(u >> 16);
}

__device__ __forceinline__ unsigned pack_bf2(float lo, float hi) {
  return (unsigned)f2bf(lo) | ((unsigned)f2bf(hi) << 16);
}

// ---------- kernel 1: weight transpose+convert: WT[z][n][k] = bf16(w_z[k][n]) ----------
__global__ __launch_bounds__(256) void wtrans_kernel(
    const float* __restrict__ wq, const float* __restrict__ wk,
    const float* __restrict__ wv, const float* __restrict__ wo,
    u16* __restrict__ dst) {
  __shared__ float t[32][33];
  const int z = blockIdx.z;
  const float* src = (z == 0) ? wq : (z == 1) ? wk : (z == 2) ? wv : wo;
  u16* d = dst + (size_t)z * 1024 * 1024;
  const int tx = threadIdx.x & 31, ty = threadIdx.x >> 5;
  const int bx = blockIdx.x * 32, by = blockIdx.y * 32;
#pragma unroll
  for (int j = 0; j < 4; j++)
    t[ty + j * 8][tx] = src[(size_t)(by + ty + j * 8) * 1024 + bx + tx];
  __syncthreads();
#pragma unroll
  for (int j = 0; j < 4; j++)
    d[(size_t)(bx + ty + j * 8) * 1024 + by + tx] = f2bf(t[tx][ty + j * 8]);
}

// ---------- kernel 2: convert q,k,v fp32 -> bf16 ----------
__global__ __launch_bounds__(256) void cvt_in_kernel(
    const float* __restrict__ q, const float* __restrict__ k,
    const float* __restrict__ v, u16* __restrict__ dst) {
  const int z = blockIdx.y;
  const float* src = (z == 0) ? q : (z == 1) ? k : v;
  u16* d = dst + (size_t)z * 4096 * 1024;
  size_t i = ((size_t)blockIdx.x * 256 + threadIdx.x) * 4;
  float4 f = *(const float4*)(src + i);
  u16x4 o;
  o.x = f2bf(f.x); o.y = f2bf(f.y); o.z = f2bf(f.z); o.w = f2bf(f.w);
  *(u16x4*)(d + i) = o;
}

// ---------- shared GEMM core: 128x128 tile, BK=64, swizzled LDS, global_load_lds ----------
__device__ __forceinline__ void gemm128(const u16* __restrict__ A,
                                        const u16* __restrict__ B,
                                        int arow0, int bcol0,
                                        u16* ldsA, u16* ldsB,
                                        f32x4 acc[4][4]) {
  const int tid = threadIdx.x;
  const int lane = tid & 63, wave = tid >> 6;
  const int lr = lane & 15, lg = lane >> 4;
  const int wr = (wave >> 1) * 64, wc = (wave & 1) * 64;
  for (int kt = 0; kt < 1024; kt += 64) {
#pragma unroll
    for (int i = 0; i < 4; i++) {
      int o = (i * 256 + tid) * 8;
      int row = o >> 6, ch = (o >> 3) & 7;
      int sc = (ch ^ (row & 7)) << 3;  // inverse-swizzled source chunk
      GLDS16(A + (size_t)(arow0 + row) * 1024 + kt + sc, &ldsA[o]);
      GLDS16(B + (size_t)(bcol0 + row) * 1024 + kt + sc, &ldsB[o]);
    }
    __syncthreads();
#pragma unroll
    for (int kk = 0; kk < 2; kk++) {
      bf16x8 af[4], bfr[4];
      const int ke = kk * 32 + lg * 8;
#pragma unroll
      for (int m = 0; m < 4; m++) {
        int row = wr + m * 16 + lr;
        af[m] = *(const bf16x8*)&ldsA[row * 64 + (ke ^ ((row & 7) << 3))];
      }
#pragma unroll
      for (int n = 0; n < 4; n++) {
        int row = wc + n * 16 + lr;
        bfr[n] = *(const bf16x8*)&ldsB[row * 64 + (ke ^ ((row & 7) << 3))];
      }
#pragma unroll
      for (int m = 0; m < 4; m++)
#pragma unroll
        for (int n = 0; n < 4; n++)
          acc[m][n] = __builtin_amdgcn_mfma_f32_16x16x32_bf16(af[m], bfr[n],
                                                              acc[m][n], 0, 0, 0);
    }
    __syncthreads();
  }
}

// ---------- kernel 3: QKV projections ----------
__global__ __launch_bounds__(256) void proj_kernel(
    const u16* __restrict__ Xb, const u16* __restrict__ WT,
    u16* __restrict__ Qh, u16* __restrict__ Kh, u16* __restrict__ Vt) {
  __shared__ u16 lds[16384];
  const int z = blockIdx.z;
  const u16* A = Xb + (size_t)z * 4096 * 1024;
  const u16* B = WT + (size_t)z * 1024 * 1024;
  const int arow0 = blockIdx.y * 128, bcol0 = blockIdx.x * 128;
  f32x4 acc[4][4] = {};
  gemm128(A, B, arow0, bcol0, lds, lds + 8192, acc);

  const int lane = threadIdx.x & 63, wave = threadIdx.x >> 6;
  const int lr = lane & 15, lg = lane >> 4;
  const int wr = (wave >> 1) * 64, wc = (wave & 1) * 64;

  if (z == 2) {
    // V: transpose through LDS -> Vt[(b*16+h)*64+d][s]
    u16* T = lds;  // [128 c][128 s], swizzled rows
#pragma unroll
    for (int m = 0; m < 4; m++)
#pragma unroll
      for (int n = 0; n < 4; n++)
#pragma unroll
        for (int r = 0; r < 4; r++) {
          int sl = wr + m * 16 + lg * 4 + r;
          int cl = wc + n * 16 + lr;
          T[cl * 128 + (sl ^ ((cl & 7) << 3))] = f2bf(acc[m][n][r]);
        }
    __syncthreads();
    const int t = threadIdx.x;
    const int cl = t >> 1, s0 = (t & 1) * 64;
    const int gc = bcol0 + cl;
    const size_t vrow = ((size_t)(arow0 >> 11) * 16 + (gc >> 6)) * 64 + (gc & 63);
#pragma unroll
    for (int j = 0; j < 8; j++) {
      int sl = s0 + j * 8;
      u16x8 vv = *(const u16x8*)&T[cl * 128 + (sl ^ ((cl & 7) << 3))];
      *(u16x8*)&Vt[vrow * 2048 + (size_t)((arow0 & 2047) + sl)] = vv;
    }
  } else {
    const float scale = (z == 0) ? 0.18033688f : 1.0f;  // 0.125 * log2(e)
    u16* dst = (z == 0) ? Qh : Kh;
#pragma unroll
    for (int m = 0; m < 4; m++)
#pragma unroll
      for (int n = 0; n < 4; n++)
#pragma unroll
        for (int r = 0; r < 4; r++) {
          int gr = arow0 + wr + m * 16 + lg * 4 + r;
          int gc = bcol0 + wc + n * 16 + lr;
          size_t idx = (((size_t)(gr >> 11) * 16 + (gc >> 6)) * 2048 +
                        (gr & 2047)) * 64 + (gc & 63);
          dst[idx] = f2bf(acc[m][n][r] * scale);
        }
  }
}

// ---------- kernel 4: flash attention (swapped QK^T, P in registers) ----------
// grid (32 qblocks, 32 bh), 4 waves/block, 16 q-rows per wave. LDS = 32KB.
// S^T = mfma(K-frag, Q-frag): lane owns q = lane&15; K rows fed through
// permutation κ(n,a)=32(n>>1)+8(a>>2)+4(n&1)+(a&3) so the lane's 16 keys are
// exactly the PV A-fragment sets {8*lg..+7} u {32+8*lg..+7} -> zero exchange.
__global__ __launch_bounds__(256, 4) void attn_kernel(
    const u16* __restrict__ Qh, const u16* __restrict__ Kh,
    const u16* __restrict__ Vt, u16* __restrict__ Ob) {
  __shared__ u16 kt[2][64 * 64];  // K tile [key][d], h-swizzled rows
  __shared__ u16 vt[2][64 * 64];  // V^T tile [d][s], xor-swizzled rows
  const int tid = threadIdx.x;
  const int lane = tid & 63, wave = tid >> 6;
  const int lr = lane & 15, lg = lane >> 4;
  const int bh = blockIdx.y;
  const int q0 = blockIdx.x * 64;
  const u16* Qb = Qh + ((size_t)bh * 2048 + q0) * 64;
  const u16* Kb = Kh + (size_t)bh * 2048 * 64;
  const u16* Vb = Vt + (size_t)bh * 64 * 2048;

  // Q fragment (B-operand of swapped QK^T; identical layout to old A-operand)
  bf16x8 aq[2];
#pragma unroll
  for (int kk = 0; kk < 2; kk++)
    aq[kk] = *(const bf16x8*)(Qb + (wave * 16 + lr) * 64 + kk * 32 + lg * 8);

  // K A-operand LDS offsets with row perm κ and bank swizzle h(κ)
  int koff[2][4];
#pragma unroll
  for (int n = 0; n < 4; n++) {
    int kr = 32 * (n >> 1) + 8 * (lr >> 2) + 4 * (n & 1) + (lr & 3);
    int h = (kr + 2 * ((kr >> 3) & 3)) & 7;
#pragma unroll
    for (int kk = 0; kk < 2; kk++)
      koff[kk][n] = kr * 64 + ((kk * 32 + lg * 8) ^ (h << 3));
  }
  // V B-operand LDS offsets
  int voff[2][4];
#pragma unroll
  for (int n = 0; n < 4; n++) {
    int d = n * 16 + lr;
#pragma unroll
    for (int ks = 0; ks < 2; ks++)
      voff[ks][n] = d * 64 + ((ks * 32 + lg * 8) ^ ((d & 7) << 3));
  }

  f32x4 oacc[4] = {};
  float mrun = -1e30f, lrun = 0.f;

  auto STAGE = [&](int t, int b) {
#pragma unroll
    for (int i = 0; i < 2; i++) {
      int o = (i * 256 + tid) * 8;
      int row = o >> 6, ch = (o >> 3) & 7;
      int hk = (row + 2 * ((row >> 3) & 3)) & 7;
      GLDS16(Kb + (size_t)(t * 64 + row) * 64 + ((ch ^ hk) << 3), &kt[b][o]);
      GLDS16(Vb + (size_t)row * 2048 + t * 64 + ((ch ^ (row & 7)) << 3),
             &vt[b][o]);
    }
  };

  auto COMPUTE = [&](int cur) {
    // S^T tile: sacc[n][r] = S[key κ(n, lg*4+r)][q=lr] (log2 domain)
    f32x4 sacc[4] = {};
#pragma unroll
    for (int kk = 0; kk < 2; kk++) {
#pragma unroll
      for (int n = 0; n < 4; n++) {
        bf16x8 ka = *(const bf16x8*)&kt[cur][koff[kk][n]];
        sacc[n] = __builtin_amdgcn_mfma_f32_16x16x32_bf16(ka, aq[kk],
                                                          sacc[n], 0, 0, 0);
      }
    }
    // in-lane max over 16 + 2 cross-lane steps (lanes sharing q = lr)
    float mx0 = fmaxf(fmaxf(sacc[0][0], sacc[0][1]), fmaxf(sacc[0][2], sacc[0][3]));
    float mx1 = fmaxf(fmaxf(sacc[1][0], sacc[1][1]), fmaxf(sacc[1][2], sacc[1][3]));
    float mx2 = fmaxf(fmaxf(sacc[2][0], sacc[2][1]), fmaxf(sacc[2][2], sacc[2][3]));
    float mx3 = fmaxf(fmaxf(sacc[3][0], sacc[3][1]), fmaxf(sacc[3][2], sacc[3][3]));
    float mx = fmaxf(fmaxf(mx0, mx1), fmaxf(mx2, mx3));
    mx = fmaxf(mx, __shfl_xor(mx, 16));
    mx = fmaxf(mx, __shfl_xor(mx, 32));
    float mnew = fmaxf(mrun, mx);
    // defer-max (T13): skip rescale when growth <= 8 (log2 domain -> p <= 256)
    if (__all(mx - mrun <= 8.0f)) {
      mnew = mrun;
    } else {
      float corr = EXP2(mrun - mnew);
      mrun = mnew;
      lrun *= corr;
      float cr[4];
#pragma unroll
      for (int r = 0; r < 4; r++) cr[r] = __shfl(corr, lg * 4 + r);
#pragma unroll
      for (int n = 0; n < 4; n++)
#pragma unroll
        for (int r = 0; r < 4; r++) oacc[n][r] *= cr[r];
    }
    // p = exp2(s - m), in place; row-sum
    float psum = 0.f;
#pragma unroll
    for (int n = 0; n < 4; n++)
#pragma unroll
      for (int r = 0; r < 4; r++) {
        float p = EXP2(sacc[n][r] - mnew);
        sacc[n][r] = p;
        psum += p;
      }
    psum += __shfl_xor(psum, 16);
    psum += __shfl_xor(psum, 32);
    lrun += psum;
    // pack P into PV A-fragments: pa[ks] = keys 32ks+8lg..+7 for q=lr
    unsigned c[8];
#pragma unroll
    for (int n = 0; n < 4; n++) {
      c[2 * n]     = pack_bf2(sacc[n][0], sacc[n][1]);
      c[2 * n + 1] = pack_bf2(sacc[n][2], sacc[n][3]);
    }
    u32x4 w0 = {c[0], c[1], c[2], c[3]};
    u32x4 w1 = {c[4], c[5], c[6], c[7]};
    bf16x8 pa0 = __builtin_bit_cast(bf16x8, w0);
    bf16x8 pa1 = __builtin_bit_cast(bf16x8, w1);
    // O += P V
#pragma unroll
    for (int ks = 0; ks < 2; ks++) {
      bf16x8 ap = ks ? pa1 : pa0;
      bf16x8 bv[4];
#pragma unroll
      for (int n = 0; n < 4; n++)
        bv[n] = *(const bf16x8*)&vt[cur][voff[ks][n]];
#pragma unroll
      for (int n = 0; n < 4; n++)
        oacc[n] = __builtin_amdgcn_mfma_f32_16x16x32_bf16(ap, bv[n],
                                                          oacc[n], 0, 0, 0);
    }
  };

  STAGE(0, 0);
  for (int t = 0; t < 31; ++t) {
    STAGE(t + 1, (t + 1) & 1);  // prefetch next tile into other buffer
    asm volatile("s_waitcnt vmcnt(4)" ::: "memory");  // tile t landed
    block_sync();
    COMPUTE(t & 1);
    block_sync();               // all waves done reading buf before overwrite
  }
  asm volatile("s_waitcnt vmcnt(0)" ::: "memory");
  block_sync();
  COMPUTE(1);  // tile 31 is in buffer 1

  // epilogue: normalize (inv lives at q=lr; oacc rows are q=lg*4+r)
  const int b = bh >> 4, h = bh & 15;
  float inv = 1.0f / lrun;
  float ivr[4];
#pragma unroll
  for (int r = 0; r < 4; r++) ivr[r] = __shfl(inv, lg * 4 + r);
#pragma unroll
  for (int r = 0; r < 4; r++) {
    int qrow = q0 + wave * 16 + lg * 4 + r;
#pragma unroll
    for (int n = 0; n < 4; n++) {
      int d = n * 16 + lr;
      Ob[((size_t)b * 2048 + qrow) * 1024 + h * 64 + d] = f2bf(oacc[n][r] * ivr[r]);
    }
  }
}

// ---------- kernel 5: output projection -> fp32 d_out ----------
__global__ __launch_bounds__(256) void outproj_kernel(
    const u16* __restrict__ Ob, const u16* __restrict__ WoT,
    float* __restrict__ out) {
  __shared__ u16 lds[16384];
  const int arow0 = blockIdx.y * 128, bcol0 = blockIdx.x * 128;
  f32x4 acc[4][4] = {};
  gemm128(Ob, WoT, arow0, bcol0, lds, lds + 8192, acc);
  const int lane = threadIdx.x & 63, wave = threadIdx.x >> 6;
  const int lr = lane & 15, lg = lane >> 4;
  const int wr = (wave >> 1) * 64, wc = (wave & 1) * 64;
#pragma unroll
  for (int m = 0; m < 4; m++)
#pragma unroll
    for (int n = 0; n < 4; n++)
#pragma unroll
      for (int r = 0; r < 4; r++) {
        int gr = arow0 + wr + m * 16 + lg * 4 + r;
        int gc = bcol0 + wc + n * 16 + lr;
        out[(size_t)gr * 1024 + gc] = acc[m][n][r];
      }
}

extern "C" void kernel_launch(void* const* d_in, const int* in_sizes, int n_in,
                              void* d_out, int out_size, void* d_ws, size_t ws_size,
                              hipStream_t stream) {
  const float* q  = (const float*)d_in[0];
  const float* k  = (const float*)d_in[1];
  const float* v  = (const float*)d_in[2];
  const float* wq = (const float*)d_in[3];
  const float* wk = (const float*)d_in[4];
  const float* wv = (const float*)d_in[5];
  const float* wo = (const float*)d_in[6];
  float* out = (float*)d_out;
  char* ws = (char*)d_ws;

  u16* WT = (u16*)ws;                                    // [4][1024][1024]
  u16* Xb = (u16*)(ws + (size_t)8  * 1024 * 1024);       // [3][4096][1024]
  u16* Qh = (u16*)(ws + (size_t)32 * 1024 * 1024);       // [32][2048][64]
  u16* Kh = (u16*)(ws + (size_t)40 * 1024 * 1024);       // [32][2048][64]
  u16* Vt = (u16*)(ws + (size_t)48 * 1024 * 1024);       // [32][64][2048]
  u16* Ob = (u16*)(ws + (size_t)56 * 1024 * 1024);       // [4096][1024]

  wtrans_kernel<<<dim3(32, 32, 4), 256, 0, stream>>>(wq, wk, wv, wo, WT);
  cvt_in_kernel<<<dim3(4096, 3), 256, 0, stream>>>(q, k, v, Xb);
  proj_kernel<<<dim3(8, 32, 3), 256, 0, stream>>>(Xb, WT, Qh, Kh, Vt);
  attn_kernel<<<dim3(32, 32), 256, 0, stream>>>(Qh, Kh, Vt, Ob);
  outproj_kernel<<<dim3(8, 32), 256, 0, stream>>>(Ob, WT + (size_t)3 * 1024 * 1024, out);
}

// Round 6
// 144.088 us; speedup vs baseline: 1.7068x; 1.0776x over previous
//
#include <hip/hip_runtime.h>
#include <hip/hip_bf16.h>

// B=2, S=2048, H=16, D=64, D_MODEL=1024, M=B*S=4096
// ws layout (bytes):
//   WT  @ 0MB  : [4][1024][1024] bf16 (w_q^T, w_k^T, w_v^T, w_o^T)  8MB
//   Xb  @ 8MB  : [3][4096][1024] bf16 (q,k,v converted)            24MB
//   Qh  @ 32MB : [32][2048][64]  bf16 (scaled by 0.125*log2e)       8MB
//   Kh  @ 40MB : [32][2048][64]  bf16                               8MB
//   Vt  @ 48MB : [32][64][2048]  bf16 (per-head transposed V)       8MB
//   Ob  @ 56MB : [4096][1024]    bf16 (attention output)            8MB

using bf16x8 = __attribute__((ext_vector_type(8))) short;
using f32x4  = __attribute__((ext_vector_type(4))) float;
using u32x4  = __attribute__((ext_vector_type(4))) unsigned;
typedef unsigned short u16;
using u16x4 = __attribute__((ext_vector_type(4))) u16;
using u16x8 = __attribute__((ext_vector_type(8))) u16;

#define GLDS16(g, l) __builtin_amdgcn_global_load_lds( \
    (const __attribute__((address_space(1))) void*)(g), \
    (__attribute__((address_space(3))) void*)(l), 16, 0, 0)

#if __has_builtin(__builtin_amdgcn_exp2f)
#define EXP2(x) __builtin_amdgcn_exp2f(x)
#else
#define EXP2(x) exp2f(x)
#endif

// Raw s_barrier is IntrNoMem: pair it with compiler memory fences so LDS
// reads/writes cannot be moved across it at compile time.
__device__ __forceinline__ void block_sync() {
  __builtin_amdgcn_sched_barrier(0);
  asm volatile("" ::: "memory");
  __builtin_amdgcn_s_barrier();
  asm volatile("" ::: "memory");
  __builtin_amdgcn_sched_barrier(0);
}

__device__ __forceinline__ u16 f2bf(float f) {
  unsigned u = __builtin_bit_cast(unsigned, f);
  u += 0x7fffu + ((u >> 16) & 1u);
  return (u16)(u >> 16);
}

// packed f32->bf16 RNE (no builtin on gfx950; T12 primitive)
__device__ __forceinline__ unsigned cvt_pk_bf16(float lo, float hi) {
  unsigned r;
  asm("v_cvt_pk_bf16_f32 %0, %1, %2" : "=v"(r) : "v"(lo), "v"(hi));
  return r;
}

__device__ __forceinline__ float fmax3(float a, float b, float c) {
  return fmaxf(fmaxf(a, b), c);  // clang fuses to v_max3_f32
}

// ---------- kernel 1: weight transpose+convert: WT[z][n][k] = bf16(w_z[k][n]) ----------
__global__ __launch_bounds__(256) void wtrans_kernel(
    const float* __restrict__ wq, const float* __restrict__ wk,
    const float* __restrict__ wv, const float* __restrict__ wo,
    u16* __restrict__ dst) {
  __shared__ float t[32][33];
  const int z = blockIdx.z;
  const float* src = (z == 0) ? wq : (z == 1) ? wk : (z == 2) ? wv : wo;
  u16* d = dst + (size_t)z * 1024 * 1024;
  const int tx = threadIdx.x & 31, ty = threadIdx.x >> 5;
  const int bx = blockIdx.x * 32, by = blockIdx.y * 32;
#pragma unroll
  for (int j = 0; j < 4; j++)
    t[ty + j * 8][tx] = src[(size_t)(by + ty + j * 8) * 1024 + bx + tx];
  __syncthreads();
#pragma unroll
  for (int j = 0; j < 4; j++)
    d[(size_t)(bx + ty + j * 8) * 1024 + by + tx] = f2bf(t[tx][ty + j * 8]);
}

// ---------- kernel 2: convert q,k,v fp32 -> bf16 ----------
__global__ __launch_bounds__(256) void cvt_in_kernel(
    const float* __restrict__ q, const float* __restrict__ k,
    const float* __restrict__ v, u16* __restrict__ dst) {
  const int z = blockIdx.y;
  const float* src = (z == 0) ? q : (z == 1) ? k : v;
  u16* d = dst + (size_t)z * 4096 * 1024;
  size_t i = ((size_t)blockIdx.x * 256 + threadIdx.x) * 4;
  float4 f = *(const float4*)(src + i);
  uint2 o2 = make_uint2(cvt_pk_bf16(f.x, f.y), cvt_pk_bf16(f.z, f.w));
  *(uint2*)(d + i) = o2;
}

// ---------- shared GEMM core: 128x128 tile, BK=64, swizzled LDS, global_load_lds ----------
__device__ __forceinline__ void gemm128(const u16* __restrict__ A,
                                        const u16* __restrict__ B,
                                        int arow0, int bcol0,
                                        u16* ldsA, u16* ldsB,
                                        f32x4 acc[4][4]) {
  const int tid = threadIdx.x;
  const int lane = tid & 63, wave = tid >> 6;
  const int lr = lane & 15, lg = lane >> 4;
  const int wr = (wave >> 1) * 64, wc = (wave & 1) * 64;
  for (int kt = 0; kt < 1024; kt += 64) {
#pragma unroll
    for (int i = 0; i < 4; i++) {
      int o = (i * 256 + tid) * 8;
      int row = o >> 6, ch = (o >> 3) & 7;
      int sc = (ch ^ (row & 7)) << 3;  // inverse-swizzled source chunk
      GLDS16(A + (size_t)(arow0 + row) * 1024 + kt + sc, &ldsA[o]);
      GLDS16(B + (size_t)(bcol0 + row) * 1024 + kt + sc, &ldsB[o]);
    }
    __syncthreads();
#pragma unroll
    for (int kk = 0; kk < 2; kk++) {
      bf16x8 af[4], bfr[4];
      const int ke = kk * 32 + lg * 8;
#pragma unroll
      for (int m = 0; m < 4; m++) {
        int row = wr + m * 16 + lr;
        af[m] = *(const bf16x8*)&ldsA[row * 64 + (ke ^ ((row & 7) << 3))];
      }
#pragma unroll
      for (int n = 0; n < 4; n++) {
        int row = wc + n * 16 + lr;
        bfr[n] = *(const bf16x8*)&ldsB[row * 64 + (ke ^ ((row & 7) << 3))];
      }
#pragma unroll
      for (int m = 0; m < 4; m++)
#pragma unroll
        for (int n = 0; n < 4; n++)
          acc[m][n] = __builtin_amdgcn_mfma_f32_16x16x32_bf16(af[m], bfr[n],
                                                              acc[m][n], 0, 0, 0);
    }
    __syncthreads();
  }
}

// ---------- kernel 3: QKV projections ----------
__global__ __launch_bounds__(256) void proj_kernel(
    const u16* __restrict__ Xb, const u16* __restrict__ WT,
    u16* __restrict__ Qh, u16* __restrict__ Kh, u16* __restrict__ Vt) {
  __shared__ u16 lds[16384];
  const int z = blockIdx.z;
  const u16* A = Xb + (size_t)z * 4096 * 1024;
  const u16* B = WT + (size_t)z * 1024 * 1024;
  const int arow0 = blockIdx.y * 128, bcol0 = blockIdx.x * 128;
  f32x4 acc[4][4] = {};
  gemm128(A, B, arow0, bcol0, lds, lds + 8192, acc);

  const int lane = threadIdx.x & 63, wave = threadIdx.x >> 6;
  const int lr = lane & 15, lg = lane >> 4;
  const int wr = (wave >> 1) * 64, wc = (wave & 1) * 64;

  if (z == 2) {
    // V: transpose through LDS -> Vt[(b*16+h)*64+d][s]
    u16* T = lds;  // [128 c][128 s], swizzled rows
#pragma unroll
    for (int m = 0; m < 4; m++)
#pragma unroll
      for (int n = 0; n < 4; n++)
#pragma unroll
        for (int r = 0; r < 4; r++) {
          int sl = wr + m * 16 + lg * 4 + r;
          int cl = wc + n * 16 + lr;
          T[cl * 128 + (sl ^ ((cl & 7) << 3))] = f2bf(acc[m][n][r]);
        }
    __syncthreads();
    const int t = threadIdx.x;
    const int cl = t >> 1, s0 = (t & 1) * 64;
    const int gc = bcol0 + cl;
    const size_t vrow = ((size_t)(arow0 >> 11) * 16 + (gc >> 6)) * 64 + (gc & 63);
#pragma unroll
    for (int j = 0; j < 8; j++) {
      int sl = s0 + j * 8;
      u16x8 vv = *(const u16x8*)&T[cl * 128 + (sl ^ ((cl & 7) << 3))];
      *(u16x8*)&Vt[vrow * 2048 + (size_t)((arow0 & 2047) + sl)] = vv;
    }
  } else {
    const float scale = (z == 0) ? 0.18033688f : 1.0f;  // 0.125 * log2(e)
    u16* dst = (z == 0) ? Qh : Kh;
#pragma unroll
    for (int m = 0; m < 4; m++)
#pragma unroll
      for (int n = 0; n < 4; n++)
#pragma unroll
        for (int r = 0; r < 4; r++) {
          int gr = arow0 + wr + m * 16 + lg * 4 + r;
          int gc = bcol0 + wc + n * 16 + lr;
          size_t idx = (((size_t)(gr >> 11) * 16 + (gc >> 6)) * 2048 +
                        (gr & 2047)) * 64 + (gc & 63);
          dst[idx] = f2bf(acc[m][n][r] * scale);
        }
  }
}

// ---------- kernel 4: flash attention (swapped QK^T, P in registers) ----------
// grid (32 qblocks, 32 bh), 4 waves/block, 16 q-rows per wave. LDS = 32KB.
// S^T = mfma(K-frag, Q-frag): lane owns q = lane&15; K rows fed through
// permutation κ(n,a)=32(n>>1)+8(a>>2)+4(n&1)+(a&3) so the lane's 16 keys are
// exactly the PV A-fragment sets {8*lg..+7} u {32+8*lg..+7} -> zero exchange.
// K bank swizzle h(kr)=(kr&3)|(((kr>>3)&1)<<2): bijective on bank-groups for
// every 8 consecutive lanes (fixes R5's 4.2M conflicts).
__global__ __launch_bounds__(256, 4) void attn_kernel(
    const u16* __restrict__ Qh, const u16* __restrict__ Kh,
    const u16* __restrict__ Vt, u16* __restrict__ Ob) {
  __shared__ u16 kt[2][64 * 64];  // K tile [key][d], h-swizzled rows
  __shared__ u16 vt[2][64 * 64];  // V^T tile [d][s], xor-swizzled rows
  const int tid = threadIdx.x;
  const int lane = tid & 63, wave = tid >> 6;
  const int lr = lane & 15, lg = lane >> 4;
  const int bh = blockIdx.y;
  const int q0 = blockIdx.x * 64;
  const u16* Qb = Qh + ((size_t)bh * 2048 + q0) * 64;
  const u16* Kb = Kh + (size_t)bh * 2048 * 64;
  const u16* Vb = Vt + (size_t)bh * 64 * 2048;

  // Q fragment (B-operand of swapped QK^T)
  bf16x8 aq[2];
#pragma unroll
  for (int kk = 0; kk < 2; kk++)
    aq[kk] = *(const bf16x8*)(Qb + (wave * 16 + lr) * 64 + kk * 32 + lg * 8);

  // K A-operand LDS offsets: perm κ, swizzle h (h depends only on lr)
  const int hsw = (lr & 3) | (((lr >> 2) & 1) << 2);
  int koff[2][4];
#pragma unroll
  for (int n = 0; n < 4; n++) {
    int kr = 32 * (n >> 1) + 8 * (lr >> 2) + 4 * (n & 1) + (lr & 3);
#pragma unroll
    for (int kk = 0; kk < 2; kk++)
      koff[kk][n] = kr * 64 + ((kk * 32 + lg * 8) ^ (hsw << 3));
  }
  // V B-operand LDS offsets
  int voff[2][4];
#pragma unroll
  for (int n = 0; n < 4; n++) {
    int d = n * 16 + lr;
#pragma unroll
    for (int ks = 0; ks < 2; ks++)
      voff[ks][n] = d * 64 + ((ks * 32 + lg * 8) ^ ((d & 7) << 3));
  }

  // hoisted staging addresses (per-lane, loop adds constant strides)
  const int o0 = tid * 8, o1 = (256 + tid) * 8;
  const u16* kg[2];
  const u16* vg[2];
#pragma unroll
  for (int i = 0; i < 2; i++) {
    int o = (i * 256 + tid) * 8;
    int row = o >> 6, ch = (o >> 3) & 7;
    int hk = (row & 3) | (((row >> 3) & 1) << 2);
    kg[i] = Kb + (size_t)row * 64 + ((ch ^ hk) << 3);
    vg[i] = Vb + (size_t)row * 2048 + ((ch ^ (row & 7)) << 3);
  }

  f32x4 oacc[4] = {};
  float mrun = -1e30f, lrun = 0.f;

  auto STAGE = [&](int t, int b) {  // b must be a literal at call site
    u16* kd = &kt[0][0] + b * 4096;
    u16* vd = &vt[0][0] + b * 4096;
    GLDS16(kg[0] + (size_t)t * 4096, kd + o0);
    GLDS16(vg[0] + t * 64, vd + o0);
    GLDS16(kg[1] + (size_t)t * 4096, kd + o1);
    GLDS16(vg[1] + t * 64, vd + o1);
  };

  auto COMPUTE = [&](int cur) {  // cur literal at call site
    // S^T tile: sacc[n][r] = S[key κ(n, lg*4+r)][q=lr] (log2 domain)
    f32x4 sacc[4] = {};
#pragma unroll
    for (int kk = 0; kk < 2; kk++) {
#pragma unroll
      for (int n = 0; n < 4; n++) {
        bf16x8 ka = *(const bf16x8*)&kt[cur][koff[kk][n]];
        sacc[n] = __builtin_amdgcn_mfma_f32_16x16x32_bf16(ka, aq[kk],
                                                          sacc[n], 0, 0, 0);
      }
    }
    // row max: 7 max3 + 1 fmax in-lane, then 2 cross-lane steps
    float t0 = fmax3(sacc[0][0], sacc[0][1], sacc[0][2]);
    float t1 = fmax3(sacc[0][3], sacc[1][0], sacc[1][1]);
    float t2 = fmax3(sacc[1][2], sacc[1][3], sacc[2][0]);
    float t3 = fmax3(sacc[2][1], sacc[2][2], sacc[2][3]);
    float t4 = fmax3(sacc[3][0], sacc[3][1], sacc[3][2]);
    float mx = fmaxf(fmax3(t0, t1, t2), fmax3(t3, t4, sacc[3][3]));
    mx = fmaxf(mx, __shfl_xor(mx, 16));
    mx = fmaxf(mx, __shfl_xor(mx, 32));
    float mnew = fmaxf(mrun, mx);
    // defer-max (T13): skip rescale when growth <= 8 (log2 domain -> p <= 256)
    if (__all(mx - mrun <= 8.0f)) {
      mnew = mrun;
    } else {
      float corr = EXP2(mrun - mnew);
      mrun = mnew;
      lrun *= corr;
      float cr[4];
#pragma unroll
      for (int r = 0; r < 4; r++) cr[r] = __shfl(corr, lg * 4 + r);
#pragma unroll
      for (int n = 0; n < 4; n++)
#pragma unroll
        for (int r = 0; r < 4; r++) oacc[n][r] *= cr[r];
    }
    // p = exp2(s - m), in place; row-sum
    float psum = 0.f;
#pragma unroll
    for (int n = 0; n < 4; n++)
#pragma unroll
      for (int r = 0; r < 4; r++) {
        float p = EXP2(sacc[n][r] - mnew);
        sacc[n][r] = p;
        psum += p;
      }
    psum += __shfl_xor(psum, 16);
    psum += __shfl_xor(psum, 32);
    lrun += psum;
    // pack P into PV A-fragments via v_cvt_pk_bf16_f32
    u32x4 w0 = {cvt_pk_bf16(sacc[0][0], sacc[0][1]),
                cvt_pk_bf16(sacc[0][2], sacc[0][3]),
                cvt_pk_bf16(sacc[1][0], sacc[1][1]),
                cvt_pk_bf16(sacc[1][2], sacc[1][3])};
    u32x4 w1 = {cvt_pk_bf16(sacc[2][0], sacc[2][1]),
                cvt_pk_bf16(sacc[2][2], sacc[2][3]),
                cvt_pk_bf16(sacc[3][0], sacc[3][1]),
                cvt_pk_bf16(sacc[3][2], sacc[3][3])};
    bf16x8 pa0 = __builtin_bit_cast(bf16x8, w0);
    bf16x8 pa1 = __builtin_bit_cast(bf16x8, w1);
    // O += P V
#pragma unroll
    for (int ks = 0; ks < 2; ks++) {
      bf16x8 ap = ks ? pa1 : pa0;
      bf16x8 bv[4];
#pragma unroll
      for (int n = 0; n < 4; n++)
        bv[n] = *(const bf16x8*)&vt[cur][voff[ks][n]];
#pragma unroll
      for (int n = 0; n < 4; n++)
        oacc[n] = __builtin_amdgcn_mfma_f32_16x16x32_bf16(ap, bv[n],
                                                          oacc[n], 0, 0, 0);
    }
  };

#define VMC4 asm volatile("s_waitcnt vmcnt(4)" ::: "memory")
  STAGE(0, 0);
  // unrolled x2 so buffer indices are compile-time (ds offsets -> immediates)
  for (int t = 0; t < 30; t += 2) {
    STAGE(t + 1, 1); VMC4; block_sync();
    COMPUTE(0); block_sync();
    STAGE(t + 2, 0); VMC4; block_sync();
    COMPUTE(1); block_sync();
  }
  STAGE(31, 1); VMC4; block_sync();
  COMPUTE(0); block_sync();
  asm volatile("s_waitcnt vmcnt(0)" ::: "memory");
  block_sync();
  COMPUTE(1);
#undef VMC4

  // epilogue: normalize (inv lives at q=lr; oacc rows are q=lg*4+r)
  const int b = bh >> 4, h = bh & 15;
  float inv = 1.0f / lrun;
  float ivr[4];
#pragma unroll
  for (int r = 0; r < 4; r++) ivr[r] = __shfl(inv, lg * 4 + r);
#pragma unroll
  for (int r = 0; r < 4; r++) {
    int qrow = q0 + wave * 16 + lg * 4 + r;
#pragma unroll
    for (int n = 0; n < 4; n++) {
      int d = n * 16 + lr;
      Ob[((size_t)b * 2048 + qrow) * 1024 + h * 64 + d] = f2bf(oacc[n][r] * ivr[r]);
    }
  }
}

// ---------- kernel 5: output projection -> fp32 d_out ----------
__global__ __launch_bounds__(256) void outproj_kernel(
    const u16* __restrict__ Ob, const u16* __restrict__ WoT,
    float* __restrict__ out) {
  __shared__ u16 lds[16384];
  const int arow0 = blockIdx.y * 128, bcol0 = blockIdx.x * 128;
  f32x4 acc[4][4] = {};
  gemm128(Ob, WoT, arow0, bcol0, lds, lds + 8192, acc);
  const int lane = threadIdx.x & 63, wave = threadIdx.x >> 6;
  const int lr = lane & 15, lg = lane >> 4;
  const int wr = (wave >> 1) * 64, wc = (wave & 1) * 64;
#pragma unroll
  for (int m = 0; m < 4; m++)
#pragma unroll
    for (int n = 0; n < 4; n++)
#pragma unroll
      for (int r = 0; r < 4; r++) {
        int gr = arow0 + wr + m * 16 + lg * 4 + r;
        int gc = bcol0 + wc + n * 16 + lr;
        out[(size_t)gr * 1024 + gc] = acc[m][n][r];
      }
}

extern "C" void kernel_launch(void* const* d_in, const int* in_sizes, int n_in,
                              void* d_out, int out_size, void* d_ws, size_t ws_size,
                              hipStream_t stream) {
  const float* q  = (const float*)d_in[0];
  const float* k  = (const float*)d_in[1];
  const float* v  = (const float*)d_in[2];
  const float* wq = (const float*)d_in[3];
  const float* wk = (const float*)d_in[4];
  const float* wv = (const float*)d_in[5];
  const float* wo = (const float*)d_in[6];
  float* out = (float*)d_out;
  char* ws = (char*)d_ws;

  u16* WT = (u16*)ws;                                    // [4][1024][1024]
  u16* Xb = (u16*)(ws + (size_t)8  * 1024 * 1024);       // [3][4096][1024]
  u16* Qh = (u16*)(ws + (size_t)32 * 1024 * 1024);       // [32][2048][64]
  u16* Kh = (u16*)(ws + (size_t)40 * 1024 * 1024);       // [32][2048][64]
  u16* Vt = (u16*)(ws + (size_t)48 * 1024 * 1024);       // [32][64][2048]
  u16* Ob = (u16*)(ws + (size_t)56 * 1024 * 1024);       // [4096][1024]

  wtrans_kernel<<<dim3(32, 32, 4), 256, 0, stream>>>(wq, wk, wv, wo, WT);
  cvt_in_kernel<<<dim3(4096, 3), 256, 0, stream>>>(q, k, v, Xb);
  proj_kernel<<<dim3(8, 32, 3), 256, 0, stream>>>(Xb, WT, Qh, Kh, Vt);
  attn_kernel<<<dim3(32, 32), 256, 0, stream>>>(Qh, Kh, Vt, Ob);
  outproj_kernel<<<dim3(8, 32), 256, 0, stream>>>(Ob, WT + (size_t)3 * 1024 * 1024, out);
}